// Round 8
// baseline (195.144 us; speedup 1.0000x reference)
//
#include <hip/hip_runtime.h>
#include <math.h>

typedef unsigned short u16;
using bf16x8 = __attribute__((ext_vector_type(8))) short;
using f32x4  = __attribute__((ext_vector_type(4))) float;

#define NS      128
#define NBLOCKS 4096    // 1 ray per block, 512 threads (8 waves)
#define NSLICE  17      // 13 (W1, slot-major K=416) + 4 (W2) slices of 4096 u16

// LDS pool (u16): 8-slot ring x 4096 u16 = 64 KB. Slice j lives at slot j&7.
// After GEMM1, h1 overlays slots {5,6,7,0} (k-slice kk -> slot (5+kk)&7) and
// h2 overlays slots {1,2,3,4} -> every epilogue writes only already-drained
// slots, so no read-drain barriers are needed (8 barriers/ray total).
#define POOLSZ 32768

// Raw barrier: drain LDS only; global register-prefetches stay in flight.
#define BAR() do { asm volatile("s_waitcnt lgkmcnt(0)" ::: "memory");        \
                   __builtin_amdgcn_s_barrier();                              \
                   asm volatile("" ::: "memory"); } while (0)

#define MF(A,B,C) __builtin_amdgcn_mfma_f32_16x16x32_bf16((A),(B),(C),0,0,0)

__device__ __forceinline__ u16 f2bf(float f) {           // host-prep path only
    unsigned int i = __float_as_uint(f);
    return (u16)((i + 0x7FFFu + ((i >> 16) & 1u)) >> 16);  // RNE
}

// pack two floats to bf16 pair [hi:lo] in one dword (single VALU op, RNE)
__device__ __forceinline__ unsigned pk(float hi, float lo) {
    unsigned r;
    asm("v_cvt_pk_bf16_f32 %0, %1, %2" : "=v"(r) : "v"(lo), "v"(hi));
    return r;
}
__device__ __forceinline__ u16 f2bf1(float f) {
    return (u16)((__float_as_uint(f) + 0x8000u) >> 16);
}

// Swizzled A-frag offsets into the h1/h2 ring slots: XOR (k>>3)&3 into the
// chunk index (readers apply chunk^quad) to spread column-wise u16 writes.
__device__ __forceinline__ int afoff_h1(int m, int k) {
    int e = (k >> 3) & 3;
    int chunk = (m >> 4) * 64 + e * 16 + (m & 15);
    return ((5 + (k >> 5)) & 7) * 4096 + (chunk ^ e) * 8 + (k & 7);
}
__device__ __forceinline__ int afoff_h2(int m, int k) {
    int e = (k >> 3) & 3;
    int chunk = (m >> 4) * 64 + e * 16 + (m & 15);
    return ((1 + (k >> 5)) & 7) * 4096 + (chunk ^ e) * 8 + (k & 7);
}

// channel/slot -> original mlp_in k index (reference ordering).
// slot: 0 = value, 1..6 = sin f0..f5, 7..12 = cos f0..f5.
__device__ __forceinline__ int orig_k(int ch, int slot) {
    if (ch < 27) {
        if (slot == 0) return ch;
        if (slot <= 6) return 30 + ch * 6 + (slot - 1);     // sin(app)
        return 192 + ch * 6 + (slot - 7);                    // cos(app)
    } else {
        int c = ch - 27;
        if (slot == 0) return 27 + c;
        if (slot <= 6) return 354 + c * 6 + (slot - 1);      // sin(view)
        return 372 + c * 6 + (slot - 7);                     // cos(view)
    }
}

// GEMM1 slice j (consumption order) holds slot cons(j): the order in which
// the device-side sin/cos chain produces slots: 0; s0,c0; s1,c1; ... s5,c5.
__device__ __forceinline__ int cons_slot(int j) {
    if (j == 0) return 0;
    return (j & 1) ? (j + 1) / 2 : 6 + j / 2;   // odd j -> sin, even -> cos
}

// W1 -> 13 slot-major slices (k = slot*32 + ch, permuted to chain order),
// W2 -> 4 slices at 53248, W3 -> 4 mini B-frag slices at 69632 (N pad 16)
__global__ __launch_bounds__(256) void prep_kernel(
    const float* __restrict__ W1, const float* __restrict__ W2,
    const float* __restrict__ W3, u16* __restrict__ ws)
{
    int idx = blockIdx.x * 256 + threadIdx.x;
    if (idx < 53248) {                               // W1r: [j13][nt8][lane64][jj8]
        int jj = idx & 7, lane = (idx >> 3) & 63, nt = (idx >> 9) & 7, j = idx >> 12;
        int q = lane >> 4, l15 = lane & 15;
        int ch = q * 8 + jj;                         // k_local = channel (0..31)
        int n = nt * 16 + l15;
        ws[idx] = (ch < 30) ? f2bf(W1[orig_k(ch, cons_slot(j)) * 128 + n]) : (u16)0;
    } else if (idx < 69632) {                        // W2r: [ks4][nt8][lane64][jj8]
        int i2 = idx - 53248;
        int jj = i2 & 7, lane = (i2 >> 3) & 63, nt = (i2 >> 9) & 7, ks = i2 >> 12;
        int k = ks * 32 + (lane >> 4) * 8 + jj;
        int n = nt * 16 + (lane & 15);
        ws[idx] = f2bf(W2[k * 128 + n]);
    } else if (idx < 71680) {                        // W3r: [ks4][lane64][jj8]
        int i3 = idx - 69632;
        int jj = i3 & 7, lane = (i3 >> 3) & 63, ks = i3 >> 9;
        int k = ks * 32 + (lane >> 4) * 8 + jj;
        int n = lane & 15;
        ws[idx] = (n < 3) ? f2bf(W3[k * 3 + n]) : (u16)0;
    }
}

// Load one slice's 2 B-frags (wave's 32-col strip) into named registers.
#define LOADB2(N0, N1, s)                                                     \
    if ((s) < NSLICE) {                                                       \
        const u16* wp = wp0 + (s) * 4096;                                     \
        N0 = *(const bf16x8*)(wp);                                            \
        N1 = *(const bf16x8*)(wp + 512);                                      \
    }

// One X-sourced K-slice: 4 A ds_reads (64-row strip, split 2+2) + 8 MFMA.
// Loads slice s+2's B-frags (3-pair rotation: pair s%3, load (s+2)%3).
#define BODYX(s, C0,C1, N0,N1)                                                \
  {                                                                           \
    LOADB2(N0, N1, (s)+2);                                                    \
    const u16* ab = pool + ((s)&7)*4096 + (wm*256 + lane)*8;                  \
    bf16x8 a0 = *(const bf16x8*)(ab);                                         \
    bf16x8 a1 = *(const bf16x8*)(ab + 512);                                   \
    __builtin_amdgcn_s_setprio(1);                                            \
    acc[0][0]=MF(a0,C0,acc[0][0]); acc[0][1]=MF(a0,C1,acc[0][1]);             \
    acc[1][0]=MF(a1,C0,acc[1][0]); acc[1][1]=MF(a1,C1,acc[1][1]);             \
    a0 = *(const bf16x8*)(ab + 1024);                                         \
    a1 = *(const bf16x8*)(ab + 1536);                                         \
    acc[2][0]=MF(a0,C0,acc[2][0]); acc[2][1]=MF(a0,C1,acc[2][1]);             \
    acc[3][0]=MF(a1,C0,acc[3][0]); acc[3][1]=MF(a1,C1,acc[3][1]);             \
    __builtin_amdgcn_s_setprio(0);                                            \
  }

// One h-sourced K-slice (GEMM2, s = 13..16): A from swizzled h1 ring slots.
#define BODYH(s, C0,C1, N0,N1)                                                \
  {                                                                           \
    LOADB2(N0, N1, (s)+2);                                                    \
    int cb = ((5 + ((s)-13)) & 7) * 512 + ((wm*256 + lane) ^ quad);           \
    bf16x8 a0 = *(const bf16x8*)(pool + cb*8);                                \
    bf16x8 a1 = *(const bf16x8*)(pool + (cb+64)*8);                           \
    __builtin_amdgcn_s_setprio(1);                                            \
    acc[0][0]=MF(a0,C0,acc[0][0]); acc[0][1]=MF(a0,C1,acc[0][1]);             \
    acc[1][0]=MF(a1,C0,acc[1][0]); acc[1][1]=MF(a1,C1,acc[1][1]);             \
    a0 = *(const bf16x8*)(pool + (cb+128)*8);                                 \
    a1 = *(const bf16x8*)(pool + (cb+192)*8);                                 \
    acc[2][0]=MF(a0,C0,acc[2][0]); acc[2][1]=MF(a0,C1,acc[2][1]);             \
    acc[3][0]=MF(a1,C0,acc[3][0]); acc[3][1]=MF(a1,C1,acc[3][1]);             \
    __builtin_amdgcn_s_setprio(0);                                            \
  }

// Write one slice's 8-channel strip (16B contiguous = one A-frag k-octet).
#define W8(j, A)                                                              \
  { uint4 w_; w_.x = pk(A[1],A[0]); w_.y = pk(A[3],A[2]);                     \
    w_.z = pk(A[5],A[4]); w_.w = pk(A[7],A[6]);                               \
    *(uint4*)(pool + ((j)&7)*4096 + bx2) = w_; }

// One doubling step for the 8 channel chains + write slices 1+2d (sin) and
// 2+2d (cos) into their ring slots.
#define DBL(d)                                                                \
  { _Pragma("unroll")                                                         \
    for (int i_ = 0; i_ < 8; ++i_) {                                          \
        float t_ = sreg[i_] * creg[i_];                                       \
        float u_ = creg[i_] * creg[i_] - sreg[i_] * sreg[i_];                 \
        sreg[i_] = t_ + t_; creg[i_] = u_;                                    \
    }                                                                         \
    W8(1 + 2*(d), sreg); W8(2 + 2*(d), creg); }

// 8 waves: wave (wm = wave>>2, wn = wave&3) owns a 64x32 output tile
// (A-amp 4 via LDS, B-amp 2 via L1/L2 registers). 8 lgkm-only barriers.
__global__ __launch_bounds__(512, 4) void render_kernel(
    const float* __restrict__ sigma_g, const float* __restrict__ app_g,
    const float* __restrict__ view_g,  const float* __restrict__ dists_g,
    const float* __restrict__ b1_g,    const float* __restrict__ b2_g,
    const float* __restrict__ b3_g,    const u16* __restrict__ ws,
    float* __restrict__ out_g)
{
    __shared__ __align__(16) u16 pool[POOLSZ];
    __shared__ __align__(16) float part[NS * 3];
    __shared__ float scanS;          // wave0 scan total broadcast
    __shared__ float sum2[6];        // per-wave final partials

    const int tid  = threadIdx.x;
    const int lane = tid & 63;
    const int wave = tid >> 6;       // 0..7
    const int l15  = lane & 15;
    const int quad = lane >> 4;
    const int wm   = wave >> 2;      // row half (64 rows)
    const int wn   = wave & 3;       // col quarter (32 cols)

    const int r  = blockIdx.x;
    const int rb = r * NS;
    const int row = tid & 127;       // X-build row (all 512 threads build)
    const int g   = tid >> 7;        // X-build channel group (8 channels)
    const float* ap = app_g  + (rb + row) * 27;
    const float* vp = view_g + (rb + row) * 3;
    // per-thread build offset within a slice: channels 8g..8g+7 of this row
    const int bx2 = ((row >> 4) * 64 + g * 16 + (row & 15)) * 8;

    // issue B loads for slices 0,1 ASAP (3-pair rotation P,Q,R)
    const u16* wp0 = ws + (wn * 128 + lane) * 8;
    bf16x8 bP0, bP1, bQ0, bQ1, bR0, bR1;
    LOADB2(bP0, bP1, 0);
    LOADB2(bQ0, bQ1, 1);

    // load this thread's 8 channel inputs (30 real, 2 pad)
    float v8[8];
    #pragma unroll
    for (int i = 0; i < 8; ++i) {
        int ch = g * 8 + i;
        v8[i] = (ch < 27) ? ap[ch] : ((ch < 30) ? vp[ch - 27] : 0.f);
    }

    // ---- alpha + shuffle transmittance scan (waves 0,1) ----
    float alpha = 0.f, prod = 1.f, wr = 0.f;
    if (tid < NS) {
        float x  = sigma_g[rb + tid] - 10.f;
        float sp = (x > 20.f) ? x : log1pf(expf(x));
        alpha = 1.f - expf(-sp * dists_g[rb + tid] * 25.f);
        if (tid == NS - 1) alpha = 1.f;
        float tb = 1.f - alpha + 1e-10f;
        prod = tb;
        #pragma unroll
        for (int d = 1; d < 64; d <<= 1) {
            float v = __shfl_up(prod, d);
            if (lane >= d) prod *= v;
        }
        if (tid == 63) scanS = prod;
    }

    // ---- chain start: sincos for 8 channels; write slices 0 (v), 1 (s0),
    // 2 (c0) into ring slots 0,1,2 ----
    float sreg[8], creg[8];
    #pragma unroll
    for (int i = 0; i < 8; ++i) {
        float rev = v8[i] * 0.15915494309189535f;
        rev -= floorf(rev);
        sreg[i] = __builtin_amdgcn_sinf(rev);
        creg[i] = __builtin_amdgcn_cosf(rev);
    }
    W8(0, v8); W8(1, sreg); W8(2, creg);
    BAR();

    // finish weights: wr = alpha * T_exclusive
    if (tid < NS) {
        float prev = __shfl_up(prod, 1);
        float base = (lane == 0) ? 1.f : prev;
        float scale = (wave == 1) ? scanS : 1.f;
        wr = alpha * base * scale;
    }

    const f32x4 vzero = {0.f, 0.f, 0.f, 0.f};
    f32x4 acc[4][2];
    #pragma unroll
    for (int mt = 0; mt < 4; ++mt)
        #pragma unroll
        for (int nt = 0; nt < 2; ++nt) acc[mt][nt] = vzero;

    // ---- GEMM1: 13 slot-major slices (pair s%3: 0=P 1=Q 2=R) ----
    BODYX(0,  bP0,bP1, bR0,bR1);
    BODYX(1,  bQ0,bQ1, bP0,bP1);
    BODYX(2,  bR0,bR1, bQ0,bQ1);
    DBL(1); DBL(2);                 // builds slices 3,4,5,6 (slots 3..6)
    BAR();
    BODYX(3,  bP0,bP1, bR0,bR1);
    BODYX(4,  bQ0,bQ1, bP0,bP1);
    BODYX(5,  bR0,bR1, bQ0,bQ1);
    BODYX(6,  bP0,bP1, bR0,bR1);
    DBL(3); DBL(4);                 // builds slices 7,8,9,10 (slots 7,0,1,2)
    BAR();
    BODYX(7,  bQ0,bQ1, bP0,bP1);
    BODYX(8,  bR0,bR1, bQ0,bQ1);
    BODYX(9,  bP0,bP1, bR0,bR1);
    BODYX(10, bQ0,bQ1, bP0,bP1);
    DBL(5);                         // builds slices 11,12 (slots 3,4)
    BAR();
    BODYX(11, bR0,bR1, bQ0,bQ1);
    // b1 issued here; latency hides under the last GEMM1 slice
    const float b1r0 = b1_g[wn * 32 + l15];
    const float b1r1 = b1_g[wn * 32 + 16 + l15];
    BODYX(12, bP0,bP1, bR0,bR1);    // loads slice 14 -> R

    // ---- epilogue 1 (no pre-barrier): h1 -> slots {5,6,7,0}, all drained;
    // concurrent slice-11/12 reads live in slots 3,4 (disjoint). ----
    #pragma unroll
    for (int mt = 0; mt < 4; ++mt)
        #pragma unroll
        for (int nt = 0; nt < 2; ++nt) {
            int col = wn * 32 + nt * 16 + l15;
            #pragma unroll
            for (int rr = 0; rr < 4; ++rr) {
                int rw = wm * 64 + mt * 16 + quad * 4 + rr;
                pool[afoff_h1(rw, col)] =
                    f2bf1(fmaxf(acc[mt][nt][rr] + ((nt == 0) ? b1r0 : b1r1), 0.f));
            }
            acc[mt][nt] = vzero;          // reset for GEMM2
        }
    BAR();   // h1 visible to all waves AND slot-3,4 reads drained

    const float b2r0 = b2_g[wn * 32 + l15];
    const float b2r1 = b2_g[wn * 32 + 16 + l15];

    // ---- GEMM2: slices 13..16 (h1 @ W2), barrier-free run ----
    BODYH(13, bQ0,bQ1, bP0,bP1);    // loads slice 15 -> P
    BODYH(14, bR0,bR1, bQ0,bQ1);    // loads slice 16 -> Q
    BODYH(15, bP0,bP1, bR0,bR1);
    BODYH(16, bQ0,bQ1, bP0,bP1);

    // ---- epilogue 2 (no pre-barrier): h2 -> slots {1,2,3,4}; concurrent
    // GEMM2 reads live in slots {5,6,7,0} (disjoint). ----
    #pragma unroll
    for (int mt = 0; mt < 4; ++mt)
        #pragma unroll
        for (int nt = 0; nt < 2; ++nt) {
            int col = wn * 32 + nt * 16 + l15;
            #pragma unroll
            for (int rr = 0; rr < 4; ++rr) {
                int rw = wm * 64 + mt * 16 + quad * 4 + rr;
                pool[afoff_h2(rw, col)] =
                    f2bf1(fmaxf(acc[mt][nt][rr] + ((nt == 0) ? b2r0 : b2r1), 0.f));
            }
        }
    BAR();   // h2 visible

    // ---- layer 3 via MFMA: rgb = sigmoid(h2 @ W3 + b3); wave = row-tile ----
    const u16* w3r = ws + 69632;
    const float b3v = (l15 < 3) ? b3_g[l15] : 0.f;
    f32x4 acc3 = vzero;
    #pragma unroll
    for (int ks = 0; ks < 4; ++ks) {
        bf16x8 w3f = *(const bf16x8*)(w3r + (ks * 64 + lane) * 8);
        int c = ((1 + ks) & 7) * 512 + ((wave * 64 + lane) ^ quad);
        bf16x8 a3 = *(const bf16x8*)(pool + c * 8);
        acc3 = MF(a3, w3f, acc3);
    }
    if (l15 < 3) {
        #pragma unroll
        for (int rr = 0; rr < 4; ++rr) {
            int rw = wave * 16 + quad * 4 + rr;
            float v = acc3[rr] + b3v;
            part[rw * 3 + l15] = 1.f / (1.f + expf(-v));
        }
    }
    BAR();

    // ---- weighted sum over samples ----
    if (tid < NS) {
        float v0 = wr * part[tid * 3 + 0];
        float v1 = wr * part[tid * 3 + 1];
        float v2 = wr * part[tid * 3 + 2];
        #pragma unroll
        for (int d = 1; d < 64; d <<= 1) {
            v0 += __shfl_xor(v0, d);
            v1 += __shfl_xor(v1, d);
            v2 += __shfl_xor(v2, d);
        }
        if (lane == 0) {
            sum2[wave * 3 + 0] = v0;
            sum2[wave * 3 + 1] = v1;
            sum2[wave * 3 + 2] = v2;
        }
    }
    BAR();
    if (tid == 0) {
        out_g[r * 3 + 0] = sum2[0] + sum2[3];
        out_g[r * 3 + 1] = sum2[1] + sum2[4];
        out_g[r * 3 + 2] = sum2[2] + sum2[5];
    }
}

extern "C" void kernel_launch(void* const* d_in, const int* in_sizes, int n_in,
                              void* d_out, int out_size, void* d_ws, size_t ws_size,
                              hipStream_t stream) {
    (void)in_sizes; (void)n_in; (void)out_size; (void)ws_size;
    const float* sigma = (const float*)d_in[0];
    const float* app   = (const float*)d_in[1];
    const float* view  = (const float*)d_in[2];
    const float* dists = (const float*)d_in[3];
    const float* W1    = (const float*)d_in[4];
    const float* b1    = (const float*)d_in[5];
    const float* W2    = (const float*)d_in[6];
    const float* b2    = (const float*)d_in[7];
    const float* W3    = (const float*)d_in[8];
    const float* b3    = (const float*)d_in[9];
    float* out = (float*)d_out;

    u16* ws = (u16*)d_ws;   // 53248 (W1r) + 16384 (W2r) + 2048 (W3r) u16 = 143360 B

    prep_kernel<<<280, 256, 0, stream>>>(W1, W2, W3, ws);
    render_kernel<<<NBLOCKS, 512, 0, stream>>>(sigma, app, view, dists,
                                               b1, b2, b3, ws, out);
}